// Round 12
// baseline (742.710 us; speedup 1.0000x reference)
//
#include <hip/hip_runtime.h>
#include <hip/hip_bf16.h>

typedef __attribute__((ext_vector_type(8))) short bf16x8;
typedef __attribute__((ext_vector_type(4))) short s16x4;
typedef __attribute__((ext_vector_type(4))) float f32x4;

__device__ __forceinline__ short f2bf(float f) {
  union { __hip_bfloat16 h; short s; } u;
  u.h = __float2bfloat16(f);
  return u.s;
}

__device__ __forceinline__ void gld_lds16(const short* g, short* l) {
  __builtin_amdgcn_global_load_lds((const __attribute__((address_space(1))) unsigned*)g,
                                   (__attribute__((address_space(3))) unsigned*)l,
                                   16, 0, 0);
}

#define BARX(N) asm volatile("s_waitcnt vmcnt(" #N ") lgkmcnt(0)\ns_barrier" ::: "memory")
#define BARLG() asm volatile("s_waitcnt lgkmcnt(0)\ns_barrier" ::: "memory")

// fp32 -> bf16 bulk convert (node_emb) + edge-count histogram, fused
__global__ void cvt_count_kernel(const float* __restrict__ in, short* __restrict__ out, long n8,
                                 const int* __restrict__ dst, int* __restrict__ cnt, int E) {
  const long T = (long)gridDim.x * blockDim.x;
  const long t0 = (long)blockIdx.x * blockDim.x + threadIdx.x;
  for (long i = t0; i < n8; i += T) {
    const float* p = in + i * 8;
    float4 a = *(const float4*)p, b = *(const float4*)(p + 4);
    bf16x8 o;
    o[0] = f2bf(a.x); o[1] = f2bf(a.y); o[2] = f2bf(a.z); o[3] = f2bf(a.w);
    o[4] = f2bf(b.x); o[5] = f2bf(b.y); o[6] = f2bf(b.z); o[7] = f2bf(b.w);
    *(bf16x8*)(out + i * 8) = o;
  }
  for (long j = t0; j < E; j += T) atomicAdd(&cnt[dst[j]], 1);
}

// All 6 weight preps in one launch. W[K][N] fp32 -> bf16 fragment slots:
// slot s = (kc*(N/16)+f)*64 + lane, lane=(kg,l16); content W[k][f*16+l16], k per PERM.
__global__ void prep_all_kernel(const float* __restrict__ eW1, const float* __restrict__ eW2,
                                const float* __restrict__ eW3, const float* __restrict__ nW1,
                                const float* __restrict__ nW2, const float* __restrict__ nW3,
                                short* __restrict__ eAll, short* __restrict__ nAll) {
  int b = blockIdx.x;
  const float* W; short* out; int K, N; bool perm;
  if (b < 48)       { W = eW1; out = eAll;          K = 384; N = 256; perm = false; }
  else if (b < 80)  { W = eW2; out = eAll + 98304;  K = 256; N = 256; perm = true;  b -= 48; }
  else if (b < 96)  { W = eW3; out = eAll + 163840; K = 256; N = 128; perm = true;  b -= 80; }
  else if (b < 128) { W = nW1; out = nAll;          K = 256; N = 256; perm = false; b -= 96; }
  else if (b < 160) { W = nW2; out = nAll + 65536;  K = 256; N = 256; perm = true;  b -= 128; }
  else              { W = nW3; out = nAll + 131072; K = 256; N = 128; perm = true;  b -= 160; }
  int s = b * 256 + threadIdx.x;
  int NF = N >> 4;
  int total = (K >> 5) * NF * 64;
  if (s >= total) return;
  int l = s & 63, kcf = s >> 6;
  int kc = kcf / NF, f = kcf - kc * NF;
  int kg = l >> 4, l16 = l & 15;
  bf16x8 o;
#pragma unroll
  for (int e = 0; e < 8; ++e) {
    int kh = kc * 32 + kg * 8 + e;
    int k = perm ? ((kh & ~63) | ((kh & 3) << 4) | ((kh >> 2) & 15)) : kh;
    o[e] = f2bf(W[(size_t)k * N + f * 16 + l16]);
  }
  *(bf16x8*)(out + (size_t)s * 8) = o;
}

// ---------------- CSR aggregation ----------------
// per-2048-node block sums
__global__ void bsum_kernel(const int* __restrict__ cnt, int* __restrict__ bsum, int N) {
  __shared__ int wsum[4];
  int b = blockIdx.x, t = threadIdx.x;
  int base = b * 2048;
  int s = 0;
#pragma unroll
  for (int j = 0; j < 8; ++j) {
    int i = base + j * 256 + t;
    s += (i < N) ? cnt[i] : 0;
  }
#pragma unroll
  for (int m = 1; m < 64; m <<= 1) s += __shfl_xor(s, m);
  if ((t & 63) == 0) wsum[t >> 6] = s;
  __syncthreads();
  if (t == 0) bsum[b] = wsum[0] + wsum[1] + wsum[2] + wsum[3];
}

// exclusive scan of block sums (nb <= 64)
__global__ void bscan_kernel(int* __restrict__ bsum, int nb) {
  int l = threadIdx.x;
  int v = (l < nb) ? bsum[l] : 0;
  int x = v;
#pragma unroll
  for (int d = 1; d < 64; d <<= 1) { int y = __shfl_up(x, d); if (l >= d) x += y; }
  if (l < nb) bsum[l] = x - v;
}

// per-node exclusive offsets using scanned block sums
__global__ void offs_kernel(const int* __restrict__ cnt, const int* __restrict__ bsum,
                            int* __restrict__ off, int* __restrict__ cursor, int N) {
  __shared__ int wpre[4];
  int b = blockIdx.x, t = threadIdx.x, w = t >> 6, l = t & 63;
  int base = b * 2048;
  int v[8];
  int s = 0;
#pragma unroll
  for (int j = 0; j < 8; ++j) {
    int i = base + t * 8 + j;
    v[j] = (i < N) ? cnt[i] : 0;
    s += v[j];
  }
  int x = s;
#pragma unroll
  for (int d = 1; d < 64; d <<= 1) { int y = __shfl_up(x, d); if (l >= d) x += y; }
  if (l == 63) wpre[w] = x;
  __syncthreads();
  int wo = 0;
  for (int k = 0; k < w; ++k) wo += wpre[k];
  int excl = bsum[b] + wo + x - s;
#pragma unroll
  for (int j = 0; j < 8; ++j) {
    int i = base + t * 8 + j;
    if (i < N) { off[i] = excl; cursor[i] = excl; }
    excl += v[j];
  }
  if (b == gridDim.x - 1 && t == 255) off[N] = excl;
}

__global__ void scatter_kernel(const int* __restrict__ dst, int* __restrict__ cursor,
                               int* __restrict__ eidx, int E) {
  int e = blockIdx.x * 256 + threadIdx.x;
  if (e < E) {
    int p = atomicAdd(&cursor[dst[e]], 1);
    eidx[p] = e;
  }
}

// per-node gather-mean of new edge embeddings -> bf16. BF=true reads the bf16 copy
// (L3-resident, half bytes); BF=false reads fp32 edge_out.
template <bool BF>
__global__ void agg_kernel(const float* __restrict__ edge_out, const short* __restrict__ edge_bf,
                           const int* __restrict__ eidx, const int* __restrict__ off,
                           short* __restrict__ aggb, int N) {
  int n = blockIdx.x * 4 + (threadIdx.x >> 6);
  if (n >= N) return;
  int l = threadIdx.x & 63;
  int beg = off[n], end = off[n + 1];
  float ax = 0.f, ay = 0.f;
  int i = beg;
  for (; i + 4 <= end; i += 4) {
#pragma unroll
    for (int j = 0; j < 4; ++j) {
      int e = eidx[i + j];
      if (BF) {
        unsigned v = *(const unsigned*)(edge_bf + (size_t)e * 128 + l * 2);
        ax += __uint_as_float(v << 16);
        ay += __uint_as_float(v & 0xffff0000u);
      } else {
        float2 v = *(const float2*)(edge_out + (size_t)e * 128 + l * 2);
        ax += v.x; ay += v.y;
      }
    }
  }
  for (; i < end; ++i) {
    int e = eidx[i];
    if (BF) {
      unsigned v = *(const unsigned*)(edge_bf + (size_t)e * 128 + l * 2);
      ax += __uint_as_float(v << 16);
      ay += __uint_as_float(v & 0xffff0000u);
    } else {
      float2 v = *(const float2*)(edge_out + (size_t)e * 128 + l * 2);
      ax += v.x; ay += v.y;
    }
  }
  float inv = 1.0f / fmaxf((float)(end - beg), 1.0f);
  unsigned pk = ((unsigned)(unsigned short)f2bf(ay * inv) << 16) |
                (unsigned)(unsigned short)f2bf(ax * inv);
  *(unsigned*)&aggb[(size_t)n * 128 + l * 2] = pk;
}

struct F8 { float4 a, b; };

// ---------------- fused 3-layer MLP + LN, BM=128, 512 thr, 112 KB LDS (R11 schedule) ----
// 16 KB weight units (K=32), TRIPLE-buffered, staged depth-2 with counted vmcnt.
// L1/L2: waves 2(row wr)x4(col wc), each 64r x 64c (4x4 frags).
// L3: row-split, wave w owns rows w*16..+15, all 128 cols; per-wave LN.
// A chunks (8 KB, K=32) triple-buffered, overlaid on Hs (dead until H1).
// H: addr(row, ch) = row*256 + (ch ^ ((row&7)<<3)); position ch holds col
// c = ((ch&3)<<4)|((ch>>2)&15) per 64-block (matches PERM'd W2/W3 K-order).
template <bool IS_EDGE>
__launch_bounds__(512)
__global__ void mlp_kernel(const float* __restrict__ node_emb_f, const float* __restrict__ edge_emb_f,
                           const short* __restrict__ node_bf, const short* __restrict__ agg_bf,
                           const int* __restrict__ src, const int* __restrict__ dst,
                           const short* __restrict__ wAll,
                           const float* __restrict__ b1, const float* __restrict__ b2,
                           const float* __restrict__ b3,
                           const float* __restrict__ gam, const float* __restrict__ bet,
                           float* __restrict__ out_base, short* __restrict__ out_bf, int M) {
  extern __shared__ short smem[];
  short* Bs = smem;            // 3 x 8192 shorts (48 KB) weight triple-buffer
  short* Hs = smem + 24576;    // 32768 shorts (64 KB); As triple overlay = first 12288 shorts

  const int tid = threadIdx.x;
  const int m0 = blockIdx.x * 128;
  const int w = tid >> 6, lane = tid & 63, l16 = lane & 15, kg = lane >> 4;
  const int wr = w >> 2, wc = w & 3;

  constexpr int NL1 = IS_EDGE ? 12 : 8;

  // A staging identity: slot tid <-> row grow, k-byte-group gcq
  const int grow = ((tid >> 6) & 7) * 16 + (tid & 15);
  const int gcq = ((tid >> 4) & 3) * 8;
  const int grc = min(m0 + grow, M - 1);
  int gsr = 0, gdr = 0;
  if (IS_EDGE) { gsr = src[grc]; gdr = dst[grc]; }

  float b1v[4], b2v[4];
#pragma unroll
  for (int ct = 0; ct < 4; ++ct) {
    int col = wc * 64 + ct * 16 + l16;
    b1v[ct] = b1[col];
    b2v[ct] = b2[col];
  }
  float b3v[8], gv[8], bev[8];
#pragma unroll
  for (int f = 0; f < 8; ++f) {
    int col = f * 16 + l16;
    b3v[f] = b3[col]; gv[f] = gam[col]; bev[f] = bet[col];
  }

  f32x4 acc[16];
#pragma unroll
  for (int i = 0; i < 16; ++i) { f32x4 z = {0.f, 0.f, 0.f, 0.f}; acc[i] = z; }

  auto stageW = [&](int v) {   // 2 vm ops/thread
    const short* g = wAll + (size_t)v * 8192;
    short* l = Bs + (size_t)(v % 3) * 8192;
    gld_lds16(g + (size_t)tid * 8, l + (size_t)tid * 8);
    gld_lds16(g + (size_t)(tid + 512) * 8, l + (size_t)(tid + 512) * 8);
  };
  auto stageAb = [&](int v) {  // bf16 source path: 1 vm op/thread, direct to LDS
    short* dstp = Hs + (size_t)(v % 3) * 4096 + (size_t)tid * 8;
    int col = v * 32 + gcq;
    const short* q;
    if (IS_EDGE) {
      q = node_bf + (size_t)(col < 128 ? gsr : gdr) * 128 + (col & 127);
    } else {
      q = (col < 128) ? node_bf + (size_t)grc * 128 + col
                      : agg_bf + (size_t)grc * 128 + (col - 128);
    }
    gld_lds16(q, dstp);
  };
  auto loadAf = [&](int v) -> F8 {  // fp32 edge region: issue loads (2 vm)
    const float* q = edge_emb_f + (size_t)grc * 128 + (v * 32 + gcq - 256);
    F8 r;
    r.a = *(const float4*)q;
    r.b = *(const float4*)(q + 4);
    return r;
  };
  auto storeAf = [&](int v, const F8& p) {  // consume + ds_write
    float t[8];
    *(float4*)t = p.a; *(float4*)(t + 4) = p.b;
    bf16x8 o;
#pragma unroll
    for (int e = 0; e < 8; ++e) o[e] = f2bf(t[e]);
    *(bf16x8*)(Hs + (size_t)(v % 3) * 4096 + (size_t)tid * 8) = o;
  };

  auto compA = [&](int u) {
    const short* Ap = Hs + (size_t)(u % 3) * 4096;
    const short* Bp = Bs + (size_t)(u % 3) * 8192;
    bf16x8 a[4], b[4];
#pragma unroll
    for (int rt = 0; rt < 4; ++rt)
      a[rt] = *(const bf16x8*)&Ap[(size_t)((wr * 4 + rt) * 64 + lane) * 8];
#pragma unroll
    for (int ct = 0; ct < 4; ++ct)
      b[ct] = *(const bf16x8*)&Bp[(size_t)((wc * 4 + ct) * 64 + lane) * 8];
#pragma unroll
    for (int rt = 0; rt < 4; ++rt)
#pragma unroll
      for (int ct = 0; ct < 4; ++ct)
        acc[rt * 4 + ct] = __builtin_amdgcn_mfma_f32_16x16x32_bf16(a[rt], b[ct], acc[rt * 4 + ct], 0, 0, 0);
  };

  auto compH = [&](int kc, const short* Bp) {
    bf16x8 a[4], b[4];
#pragma unroll
    for (int rt = 0; rt < 4; ++rt) {
      int row = wr * 64 + rt * 16 + l16;
      int ch = (kc * 32 + kg * 8) ^ ((row & 7) << 3);
      a[rt] = *(const bf16x8*)&Hs[(size_t)row * 256 + ch];
    }
#pragma unroll
    for (int ct = 0; ct < 4; ++ct)
      b[ct] = *(const bf16x8*)&Bp[(size_t)((wc * 4 + ct) * 64 + lane) * 8];
#pragma unroll
    for (int rt = 0; rt < 4; ++rt)
#pragma unroll
      for (int ct = 0; ct < 4; ++ct)
        acc[rt * 4 + ct] = __builtin_amdgcn_mfma_f32_16x16x32_bf16(a[rt], b[ct], acc[rt * 4 + ct], 0, 0, 0);
  };

  auto writeH = [&](const float* bv) {
#pragma unroll
    for (int rt = 0; rt < 4; ++rt)
#pragma unroll
      for (int q = 0; q < 4; ++q) {
        int row = wr * 64 + rt * 16 + kg * 4 + q;
        s16x4 v;
#pragma unroll
        for (int ct = 0; ct < 4; ++ct)
          v[ct] = f2bf(fmaxf(acc[rt * 4 + ct][q] + bv[ct], 0.f));
        int ch = (wc * 64 + l16 * 4) ^ ((row & 7) << 3);
        *(s16x4*)&Hs[(size_t)row * 256 + ch] = v;
      }
#pragma unroll
    for (int i = 0; i < 16; ++i) { f32x4 z = {0.f, 0.f, 0.f, 0.f}; acc[i] = z; }
  };

  auto compL3 = [&](int kk, const short* Bp) {  // row-split: wave w rows w*16..+15, 128 cols
    int row = w * 16 + l16;
    int ch = (kk * 32 + kg * 8) ^ ((row & 7) << 3);
    bf16x8 a = *(const bf16x8*)&Hs[(size_t)row * 256 + ch];
    const short* Bsub = Bp + (size_t)(kk & 1) * 4096;
#pragma unroll
    for (int f = 0; f < 8; ++f) {
      bf16x8 b = *(const bf16x8*)&Bsub[(size_t)(f * 64 + lane) * 8];
      acc[f] = __builtin_amdgcn_mfma_f32_16x16x32_bf16(a, b, acc[f], 0, 0, 0);
    }
  };

  // ---- prologue: issue order W0,A0,W1,A1 so BARX(3) drains {W0,A0}, leaves {W1,A1} ----
  stageW(0);
  stageAb(0);
  stageW(1);
  stageAb(1);
  BARX(3);

  // ---- L1 sub-loop A: u in [0,6) — stages A(2..7), all bf16 (1 vm) ----
#pragma unroll 1
  for (int u = 0; u < 6; ++u) {
    stageW(u + 2);
    stageAb(u + 2);
    compA(u);
    BARX(3);
  }

  if (IS_EDGE) {
    // ---- L1 sub-loop B: u in [6,10) — stages A(8..11), fp32 load-early/store-late ----
#pragma unroll 1
    for (int u = 6; u < 10; ++u) {
      F8 p = loadAf(u + 2);   // issue loads FIRST (FIFO: consume drains older, leaves W)
      stageW(u + 2);
      compA(u);
      storeAf(u + 2, p);      // consume (implicit wait drains through these loads)
      BARX(2);
    }
  }

  // ---- L1 sub-loop C: u in [NL1-2, NL1) — no A staging ----
#pragma unroll 1
  for (int u = NL1 - 2; u < NL1; ++u) {
    stageW(u + 2);
    compA(u);
    BARX(2);
  }
  writeH(b1v);
  BARLG();

  // ---- layer 2: u in [NL1, NL1+8) ----
#pragma unroll 1
  for (int u = NL1; u < NL1 + 8; ++u) {
    stageW(u + 2);
    compH(u - NL1, Bs + (size_t)(u % 3) * 8192);
    BARX(2);
  }
  writeH(b2v);
  BARLG();

  // ---- layer 3: 4 units x 2 chunks ----
  {
    const int us = NL1 + 8;
#pragma unroll 1
    for (int k = 0; k < 2; ++k) {
      int u = us + k;
      stageW(u + 2);
      const short* Bp = Bs + (size_t)(u % 3) * 8192;
      compL3(2 * k, Bp);
      compL3(2 * k + 1, Bp);
      BARX(2);
    }
    {
      const short* Bp = Bs + (size_t)((us + 2) % 3) * 8192;
      compL3(4, Bp);
      compL3(5, Bp);
      BARX(0);
    }
    {
      const short* Bp = Bs + (size_t)((us + 3) % 3) * 8192;
      compL3(6, Bp);
      compL3(7, Bp);
    }
  }

  // ---- epilogue: bias + per-wave LayerNorm + residual (+ optional bf16 copy) ----
#pragma unroll
  for (int q = 0; q < 4; ++q) {
    int rg = m0 + w * 16 + kg * 4 + q;
    float o[8], s1 = 0.f, s2 = 0.f;
#pragma unroll
    for (int f = 0; f < 8; ++f) {
      float x = acc[f][q] + b3v[f];
      o[f] = x; s1 += x; s2 += x * x;
    }
#pragma unroll
    for (int m = 1; m <= 8; m <<= 1) { s1 += __shfl_xor(s1, m); s2 += __shfl_xor(s2, m); }
    float mu = s1 * (1.f / 128.f);
    float var = s2 * (1.f / 128.f) - mu * mu;
    float rs = rsqrtf(var + 1e-5f);
    if (rg < M) {
      const float* resid = (IS_EDGE ? edge_emb_f : node_emb_f) + (size_t)rg * 128;
      float* op = out_base + (size_t)rg * 128;
#pragma unroll
      for (int f = 0; f < 8; ++f) {
        int col = f * 16 + l16;
        float y = (o[f] - mu) * rs * gv[f] + bev[f] + resid[col];
        op[col] = y;
        if (IS_EDGE && out_bf) out_bf[(size_t)rg * 128 + col] = f2bf(y);
      }
    }
  }
}

extern "C" void kernel_launch(void* const* d_in, const int* in_sizes, int n_in,
                              void* d_out, int out_size, void* d_ws, size_t ws_size,
                              hipStream_t stream) {
  const float* node_emb = (const float*)d_in[0];
  const float* edge_emb = (const float*)d_in[1];
  const int*   src      = (const int*)d_in[2];
  const int*   dst      = (const int*)d_in[3];
  const float* eW1 = (const float*)d_in[5];
  const float* eb1 = (const float*)d_in[6];
  const float* eW2 = (const float*)d_in[7];
  const float* eb2 = (const float*)d_in[8];
  const float* eW3 = (const float*)d_in[9];
  const float* eb3 = (const float*)d_in[10];
  const float* eg  = (const float*)d_in[11];
  const float* ebt = (const float*)d_in[12];
  const float* nW1 = (const float*)d_in[13];
  const float* nb1 = (const float*)d_in[14];
  const float* nW2 = (const float*)d_in[15];
  const float* nb2 = (const float*)d_in[16];
  const float* nW3 = (const float*)d_in[17];
  const float* nb3 = (const float*)d_in[18];
  const float* ng  = (const float*)d_in[19];
  const float* nbt = (const float*)d_in[20];

  const int Nn = in_sizes[0] / 128;
  const int Ee = in_sizes[2];
  const int nb2048 = (Nn + 2047) / 2048;   // <= 64 required by bscan_kernel

  char* ws0 = (char*)d_ws;
  char* ws = ws0;
  short* aggb   = (short*)ws;  ws += (size_t)Nn * 128 * 2;
  short* nodebf = (short*)ws;  ws += (size_t)Nn * 128 * 2;
  int* cnt_i  = (int*)ws;      ws += (size_t)Nn * 4;
  int* cursor = (int*)ws;      ws += (size_t)Nn * 4;
  int* offv   = (int*)ws;      ws += (size_t)(Nn + 1) * 4;
  int* eidx   = (int*)ws;      ws += (size_t)Ee * 4;
  int* bsum   = (int*)ws;      ws += 64 * 4;
  ws = (char*)(((uintptr_t)ws + 15) & ~(uintptr_t)15);
  short* eAll = (short*)ws;          // W1 12x8192 | W2 8x8192 | W3 8x4096 = 196608 shorts
  short* nAll = eAll + 196608;       // W1 8x8192 | W2 8x8192 | W3 8x4096 = 163840 shorts
  char* after = (char*)(nAll + 163840);
  after = (char*)(((uintptr_t)after + 15) & ~(uintptr_t)15);
  // optional bf16 copy of edge output (164 MB) if workspace allows -> L3-resident agg reads
  short* edge_bf = nullptr;
  if ((size_t)(after - ws0) + (size_t)Ee * 128 * 2 <= ws_size)
    edge_bf = (short*)after;

  float* out_node = (float*)d_out;
  float* out_edge = out_node + (size_t)Nn * 128;

  hipMemsetAsync(cnt_i, 0, (size_t)Nn * 4, stream);

  cvt_count_kernel<<<2048, 256, 0, stream>>>(node_emb, nodebf, (long)Nn * 16, dst, cnt_i, Ee);
  prep_all_kernel<<<176, 256, 0, stream>>>(eW1, eW2, eW3, nW1, nW2, nW3, eAll, nAll);

  bsum_kernel<<<nb2048, 256, 0, stream>>>(cnt_i, bsum, Nn);
  bscan_kernel<<<1, 64, 0, stream>>>(bsum, nb2048);
  offs_kernel<<<nb2048, 256, 0, stream>>>(cnt_i, bsum, offv, cursor, Nn);
  scatter_kernel<<<(Ee + 255) / 256, 256, 0, stream>>>(dst, cursor, eidx, Ee);

  mlp_kernel<true><<<(Ee + 127) / 128, 512, 114688, stream>>>(
      node_emb, edge_emb, nodebf, aggb, src, dst, eAll,
      eb1, eb2, eb3, eg, ebt, out_edge, edge_bf, Ee);

  if (edge_bf)
    agg_kernel<true><<<(Nn + 3) / 4, 256, 0, stream>>>(out_edge, edge_bf, eidx, offv, aggb, Nn);
  else
    agg_kernel<false><<<(Nn + 3) / 4, 256, 0, stream>>>(out_edge, edge_bf, eidx, offv, aggb, Nn);

  mlp_kernel<false><<<(Nn + 127) / 128, 512, 114688, stream>>>(
      node_emb, edge_emb, nodebf, aggb, src, dst, nAll,
      nb1, nb2, nb3, ng, nbt, out_node, nullptr, Nn);
}

// Round 13
// 654.173 us; speedup vs baseline: 1.1353x; 1.1353x over previous
//
#include <hip/hip_runtime.h>
#include <hip/hip_bf16.h>

typedef __attribute__((ext_vector_type(8))) short bf16x8;
typedef __attribute__((ext_vector_type(4))) short s16x4;
typedef __attribute__((ext_vector_type(4))) float f32x4;

__device__ __forceinline__ short f2bf(float f) {
  union { __hip_bfloat16 h; short s; } u;
  u.h = __float2bfloat16(f);
  return u.s;
}

__device__ __forceinline__ void gld_lds16(const short* g, short* l) {
  __builtin_amdgcn_global_load_lds((const __attribute__((address_space(1))) unsigned*)g,
                                   (__attribute__((address_space(3))) unsigned*)l,
                                   16, 0, 0);
}

#define BARX(N) asm volatile("s_waitcnt vmcnt(" #N ") lgkmcnt(0)\ns_barrier" ::: "memory")
#define BARLG() asm volatile("s_waitcnt lgkmcnt(0)\ns_barrier" ::: "memory")

// fp32 -> bf16 bulk convert (node_emb) + edge-count histogram, fused
__global__ void cvt_count_kernel(const float* __restrict__ in, short* __restrict__ out, long n8,
                                 const int* __restrict__ dst, int* __restrict__ cnt, int E) {
  const long T = (long)gridDim.x * blockDim.x;
  const long t0 = (long)blockIdx.x * blockDim.x + threadIdx.x;
  for (long i = t0; i < n8; i += T) {
    const float* p = in + i * 8;
    float4 a = *(const float4*)p, b = *(const float4*)(p + 4);
    bf16x8 o;
    o[0] = f2bf(a.x); o[1] = f2bf(a.y); o[2] = f2bf(a.z); o[3] = f2bf(a.w);
    o[4] = f2bf(b.x); o[5] = f2bf(b.y); o[6] = f2bf(b.z); o[7] = f2bf(b.w);
    *(bf16x8*)(out + i * 8) = o;
  }
  for (long j = t0; j < E; j += T) atomicAdd(&cnt[dst[j]], 1);
}

// All 6 weight preps in one launch. W[K][N] fp32 -> bf16 fragment slots:
// slot s = (kc*(N/16)+f)*64 + lane, lane=(kg,l16); content W[k][f*16+l16], k per PERM.
__global__ void prep_all_kernel(const float* __restrict__ eW1, const float* __restrict__ eW2,
                                const float* __restrict__ eW3, const float* __restrict__ nW1,
                                const float* __restrict__ nW2, const float* __restrict__ nW3,
                                short* __restrict__ eAll, short* __restrict__ nAll) {
  int b = blockIdx.x;
  const float* W; short* out; int K, N; bool perm;
  if (b < 48)       { W = eW1; out = eAll;          K = 384; N = 256; perm = false; }
  else if (b < 80)  { W = eW2; out = eAll + 98304;  K = 256; N = 256; perm = true;  b -= 48; }
  else if (b < 96)  { W = eW3; out = eAll + 163840; K = 256; N = 128; perm = true;  b -= 80; }
  else if (b < 128) { W = nW1; out = nAll;          K = 256; N = 256; perm = false; b -= 96; }
  else if (b < 160) { W = nW2; out = nAll + 65536;  K = 256; N = 256; perm = true;  b -= 128; }
  else              { W = nW3; out = nAll + 131072; K = 256; N = 128; perm = true;  b -= 160; }
  int s = b * 256 + threadIdx.x;
  int NF = N >> 4;
  int total = (K >> 5) * NF * 64;
  if (s >= total) return;
  int l = s & 63, kcf = s >> 6;
  int kc = kcf / NF, f = kcf - kc * NF;
  int kg = l >> 4, l16 = l & 15;
  bf16x8 o;
#pragma unroll
  for (int e = 0; e < 8; ++e) {
    int kh = kc * 32 + kg * 8 + e;
    int k = perm ? ((kh & ~63) | ((kh & 3) << 4) | ((kh >> 2) & 15)) : kh;
    o[e] = f2bf(W[(size_t)k * N + f * 16 + l16]);
  }
  *(bf16x8*)(out + (size_t)s * 8) = o;
}

// ---------------- CSR aggregation ----------------
// per-2048-node block sums
__global__ void bsum_kernel(const int* __restrict__ cnt, int* __restrict__ bsum, int N) {
  __shared__ int wsum[4];
  int b = blockIdx.x, t = threadIdx.x;
  int base = b * 2048;
  int s = 0;
#pragma unroll
  for (int j = 0; j < 8; ++j) {
    int i = base + j * 256 + t;
    s += (i < N) ? cnt[i] : 0;
  }
#pragma unroll
  for (int m = 1; m < 64; m <<= 1) s += __shfl_xor(s, m);
  if ((t & 63) == 0) wsum[t >> 6] = s;
  __syncthreads();
  if (t == 0) bsum[b] = wsum[0] + wsum[1] + wsum[2] + wsum[3];
}

// exclusive scan of block sums (nb <= 64)
__global__ void bscan_kernel(int* __restrict__ bsum, int nb) {
  int l = threadIdx.x;
  int v = (l < nb) ? bsum[l] : 0;
  int x = v;
#pragma unroll
  for (int d = 1; d < 64; d <<= 1) { int y = __shfl_up(x, d); if (l >= d) x += y; }
  if (l < nb) bsum[l] = x - v;
}

// per-node exclusive offsets using scanned block sums
__global__ void offs_kernel(const int* __restrict__ cnt, const int* __restrict__ bsum,
                            int* __restrict__ off, int* __restrict__ cursor, int N) {
  __shared__ int wpre[4];
  int b = blockIdx.x, t = threadIdx.x, w = t >> 6, l = t & 63;
  int base = b * 2048;
  int v[8];
  int s = 0;
#pragma unroll
  for (int j = 0; j < 8; ++j) {
    int i = base + t * 8 + j;
    v[j] = (i < N) ? cnt[i] : 0;
    s += v[j];
  }
  int x = s;
#pragma unroll
  for (int d = 1; d < 64; d <<= 1) { int y = __shfl_up(x, d); if (l >= d) x += y; }
  if (l == 63) wpre[w] = x;
  __syncthreads();
  int wo = 0;
  for (int k = 0; k < w; ++k) wo += wpre[k];
  int excl = bsum[b] + wo + x - s;
#pragma unroll
  for (int j = 0; j < 8; ++j) {
    int i = base + t * 8 + j;
    if (i < N) { off[i] = excl; cursor[i] = excl; }
    excl += v[j];
  }
  if (b == gridDim.x - 1 && t == 255) off[N] = excl;
}

__global__ void scatter_kernel(const int* __restrict__ dst, int* __restrict__ cursor,
                               int* __restrict__ eidx, int E) {
  int e = blockIdx.x * 256 + threadIdx.x;
  if (e < E) {
    int p = atomicAdd(&cursor[dst[e]], 1);
    eidx[p] = e;
  }
}

// per-node gather-mean of new edge embeddings -> bf16 (fp32 source)
__global__ void agg_kernel(const float* __restrict__ edge_out, const int* __restrict__ eidx,
                           const int* __restrict__ off, short* __restrict__ aggb, int N) {
  int n = blockIdx.x * 4 + (threadIdx.x >> 6);
  if (n >= N) return;
  int l = threadIdx.x & 63;
  int beg = off[n], end = off[n + 1];
  float ax = 0.f, ay = 0.f;
  int i = beg;
  for (; i + 4 <= end; i += 4) {
    int e0 = eidx[i], e1 = eidx[i + 1], e2 = eidx[i + 2], e3 = eidx[i + 3];
    float2 v0 = *(const float2*)(edge_out + (size_t)e0 * 128 + l * 2);
    float2 v1 = *(const float2*)(edge_out + (size_t)e1 * 128 + l * 2);
    float2 v2 = *(const float2*)(edge_out + (size_t)e2 * 128 + l * 2);
    float2 v3 = *(const float2*)(edge_out + (size_t)e3 * 128 + l * 2);
    ax += v0.x + v1.x + v2.x + v3.x;
    ay += v0.y + v1.y + v2.y + v3.y;
  }
  for (; i < end; ++i) {
    int e = eidx[i];
    float2 v = *(const float2*)(edge_out + (size_t)e * 128 + l * 2);
    ax += v.x; ay += v.y;
  }
  float inv = 1.0f / fmaxf((float)(end - beg), 1.0f);
  unsigned pk = ((unsigned)(unsigned short)f2bf(ay * inv) << 16) |
                (unsigned)(unsigned short)f2bf(ax * inv);
  *(unsigned*)&aggb[(size_t)n * 128 + l * 2] = pk;
}

struct F8 { float4 a, b; };

// ---------------- fused 3-layer MLP + LN, BM=128, 512 thr, 112 KB LDS (R11 schedule) ----
// 16 KB weight units (K=32), TRIPLE-buffered, staged depth-2 with counted vmcnt.
// L1/L2: waves 2(row wr)x4(col wc), each 64r x 64c (4x4 frags).
// L3: row-split, wave w owns rows w*16..+15, all 128 cols; per-wave LN.
// A chunks (8 KB, K=32) triple-buffered, overlaid on Hs (dead until H1).
// H: addr(row, ch) = row*256 + (ch ^ ((row&7)<<3)); position ch holds col
// c = ((ch&3)<<4)|((ch>>2)&15) per 64-block (matches PERM'd W2/W3 K-order).
template <bool IS_EDGE>
__launch_bounds__(512)
__global__ void mlp_kernel(const float* __restrict__ node_emb_f, const float* __restrict__ edge_emb_f,
                           const short* __restrict__ node_bf, const short* __restrict__ agg_bf,
                           const int* __restrict__ src, const int* __restrict__ dst,
                           const short* __restrict__ wAll,
                           const float* __restrict__ b1, const float* __restrict__ b2,
                           const float* __restrict__ b3,
                           const float* __restrict__ gam, const float* __restrict__ bet,
                           float* __restrict__ out_base, int M) {
  extern __shared__ short smem[];
  short* Bs = smem;            // 3 x 8192 shorts (48 KB) weight triple-buffer
  short* Hs = smem + 24576;    // 32768 shorts (64 KB); As triple overlay = first 12288 shorts

  const int tid = threadIdx.x;
  const int m0 = blockIdx.x * 128;
  const int w = tid >> 6, lane = tid & 63, l16 = lane & 15, kg = lane >> 4;
  const int wr = w >> 2, wc = w & 3;

  constexpr int NL1 = IS_EDGE ? 12 : 8;

  // A staging identity: slot tid <-> row grow, k-byte-group gcq
  const int grow = ((tid >> 6) & 7) * 16 + (tid & 15);
  const int gcq = ((tid >> 4) & 3) * 8;
  const int grc = min(m0 + grow, M - 1);
  int gsr = 0, gdr = 0;
  if (IS_EDGE) { gsr = src[grc]; gdr = dst[grc]; }

  float b1v[4], b2v[4];
#pragma unroll
  for (int ct = 0; ct < 4; ++ct) {
    int col = wc * 64 + ct * 16 + l16;
    b1v[ct] = b1[col];
    b2v[ct] = b2[col];
  }
  float b3v[8], gv[8], bev[8];
#pragma unroll
  for (int f = 0; f < 8; ++f) {
    int col = f * 16 + l16;
    b3v[f] = b3[col]; gv[f] = gam[col]; bev[f] = bet[col];
  }

  f32x4 acc[16];
#pragma unroll
  for (int i = 0; i < 16; ++i) { f32x4 z = {0.f, 0.f, 0.f, 0.f}; acc[i] = z; }

  auto stageW = [&](int v) {   // 2 vm ops/thread
    const short* g = wAll + (size_t)v * 8192;
    short* l = Bs + (size_t)(v % 3) * 8192;
    gld_lds16(g + (size_t)tid * 8, l + (size_t)tid * 8);
    gld_lds16(g + (size_t)(tid + 512) * 8, l + (size_t)(tid + 512) * 8);
  };
  auto stageAb = [&](int v) {  // bf16 source path: 1 vm op/thread, direct to LDS
    short* dstp = Hs + (size_t)(v % 3) * 4096 + (size_t)tid * 8;
    int col = v * 32 + gcq;
    const short* q;
    if (IS_EDGE) {
      q = node_bf + (size_t)(col < 128 ? gsr : gdr) * 128 + (col & 127);
    } else {
      q = (col < 128) ? node_bf + (size_t)grc * 128 + col
                      : agg_bf + (size_t)grc * 128 + (col - 128);
    }
    gld_lds16(q, dstp);
  };
  auto loadAf = [&](int v) -> F8 {  // fp32 edge region: issue loads (2 vm)
    const float* q = edge_emb_f + (size_t)grc * 128 + (v * 32 + gcq - 256);
    F8 r;
    r.a = *(const float4*)q;
    r.b = *(const float4*)(q + 4);
    return r;
  };
  auto storeAf = [&](int v, const F8& p) {  // consume + ds_write
    float t[8];
    *(float4*)t = p.a; *(float4*)(t + 4) = p.b;
    bf16x8 o;
#pragma unroll
    for (int e = 0; e < 8; ++e) o[e] = f2bf(t[e]);
    *(bf16x8*)(Hs + (size_t)(v % 3) * 4096 + (size_t)tid * 8) = o;
  };

  auto compA = [&](int u) {
    const short* Ap = Hs + (size_t)(u % 3) * 4096;
    const short* Bp = Bs + (size_t)(u % 3) * 8192;
    bf16x8 a[4], b[4];
#pragma unroll
    for (int rt = 0; rt < 4; ++rt)
      a[rt] = *(const bf16x8*)&Ap[(size_t)((wr * 4 + rt) * 64 + lane) * 8];
#pragma unroll
    for (int ct = 0; ct < 4; ++ct)
      b[ct] = *(const bf16x8*)&Bp[(size_t)((wc * 4 + ct) * 64 + lane) * 8];
#pragma unroll
    for (int rt = 0; rt < 4; ++rt)
#pragma unroll
      for (int ct = 0; ct < 4; ++ct)
        acc[rt * 4 + ct] = __builtin_amdgcn_mfma_f32_16x16x32_bf16(a[rt], b[ct], acc[rt * 4 + ct], 0, 0, 0);
  };

  auto compH = [&](int kc, const short* Bp) {
    bf16x8 a[4], b[4];
#pragma unroll
    for (int rt = 0; rt < 4; ++rt) {
      int row = wr * 64 + rt * 16 + l16;
      int ch = (kc * 32 + kg * 8) ^ ((row & 7) << 3);
      a[rt] = *(const bf16x8*)&Hs[(size_t)row * 256 + ch];
    }
#pragma unroll
    for (int ct = 0; ct < 4; ++ct)
      b[ct] = *(const bf16x8*)&Bp[(size_t)((wc * 4 + ct) * 64 + lane) * 8];
#pragma unroll
    for (int rt = 0; rt < 4; ++rt)
#pragma unroll
      for (int ct = 0; ct < 4; ++ct)
        acc[rt * 4 + ct] = __builtin_amdgcn_mfma_f32_16x16x32_bf16(a[rt], b[ct], acc[rt * 4 + ct], 0, 0, 0);
  };

  auto writeH = [&](const float* bv) {
#pragma unroll
    for (int rt = 0; rt < 4; ++rt)
#pragma unroll
      for (int q = 0; q < 4; ++q) {
        int row = wr * 64 + rt * 16 + kg * 4 + q;
        s16x4 v;
#pragma unroll
        for (int ct = 0; ct < 4; ++ct)
          v[ct] = f2bf(fmaxf(acc[rt * 4 + ct][q] + bv[ct], 0.f));
        int ch = (wc * 64 + l16 * 4) ^ ((row & 7) << 3);
        *(s16x4*)&Hs[(size_t)row * 256 + ch] = v;
      }
#pragma unroll
    for (int i = 0; i < 16; ++i) { f32x4 z = {0.f, 0.f, 0.f, 0.f}; acc[i] = z; }
  };

  auto compL3 = [&](int kk, const short* Bp) {  // row-split: wave w rows w*16..+15, 128 cols
    int row = w * 16 + l16;
    int ch = (kk * 32 + kg * 8) ^ ((row & 7) << 3);
    bf16x8 a = *(const bf16x8*)&Hs[(size_t)row * 256 + ch];
    const short* Bsub = Bp + (size_t)(kk & 1) * 4096;
#pragma unroll
    for (int f = 0; f < 8; ++f) {
      bf16x8 b = *(const bf16x8*)&Bsub[(size_t)(f * 64 + lane) * 8];
      acc[f] = __builtin_amdgcn_mfma_f32_16x16x32_bf16(a, b, acc[f], 0, 0, 0);
    }
  };

  // ---- prologue: issue order W0,A0,W1,A1 so BARX(3) drains {W0,A0}, leaves {W1,A1} ----
  stageW(0);
  stageAb(0);
  stageW(1);
  stageAb(1);
  BARX(3);

  // ---- L1 sub-loop A: u in [0,6) — stages A(2..7), all bf16 (1 vm) ----
#pragma unroll 1
  for (int u = 0; u < 6; ++u) {
    stageW(u + 2);
    stageAb(u + 2);
    compA(u);
    BARX(3);
  }

  if (IS_EDGE) {
    // ---- L1 sub-loop B: u in [6,10) — stages A(8..11), fp32 load-early/store-late ----
#pragma unroll 1
    for (int u = 6; u < 10; ++u) {
      F8 p = loadAf(u + 2);   // issue loads FIRST (FIFO: consume drains older, leaves W)
      stageW(u + 2);
      compA(u);
      storeAf(u + 2, p);      // consume (implicit wait drains through these loads)
      BARX(2);
    }
  }

  // ---- L1 sub-loop C: u in [NL1-2, NL1) — no A staging ----
#pragma unroll 1
  for (int u = NL1 - 2; u < NL1; ++u) {
    stageW(u + 2);
    compA(u);
    BARX(2);
  }
  writeH(b1v);
  BARLG();

  // ---- layer 2: u in [NL1, NL1+8) ----
#pragma unroll 1
  for (int u = NL1; u < NL1 + 8; ++u) {
    stageW(u + 2);
    compH(u - NL1, Bs + (size_t)(u % 3) * 8192);
    BARX(2);
  }
  writeH(b2v);
  BARLG();

  // ---- layer 3: 4 units x 2 chunks ----
  {
    const int us = NL1 + 8;
#pragma unroll 1
    for (int k = 0; k < 2; ++k) {
      int u = us + k;
      stageW(u + 2);
      const short* Bp = Bs + (size_t)(u % 3) * 8192;
      compL3(2 * k, Bp);
      compL3(2 * k + 1, Bp);
      BARX(2);
    }
    {
      const short* Bp = Bs + (size_t)((us + 2) % 3) * 8192;
      compL3(4, Bp);
      compL3(5, Bp);
      BARX(0);
    }
    {
      const short* Bp = Bs + (size_t)((us + 3) % 3) * 8192;
      compL3(6, Bp);
      compL3(7, Bp);
    }
  }

  // ---- epilogue: bias + per-wave LayerNorm + residual ----
#pragma unroll
  for (int q = 0; q < 4; ++q) {
    int rg = m0 + w * 16 + kg * 4 + q;
    float o[8], s1 = 0.f, s2 = 0.f;
#pragma unroll
    for (int f = 0; f < 8; ++f) {
      float x = acc[f][q] + b3v[f];
      o[f] = x; s1 += x; s2 += x * x;
    }
#pragma unroll
    for (int m = 1; m <= 8; m <<= 1) { s1 += __shfl_xor(s1, m); s2 += __shfl_xor(s2, m); }
    float mu = s1 * (1.f / 128.f);
    float var = s2 * (1.f / 128.f) - mu * mu;
    float rs = rsqrtf(var + 1e-5f);
    if (rg < M) {
      const float* resid = (IS_EDGE ? edge_emb_f : node_emb_f) + (size_t)rg * 128;
      float* op = out_base + (size_t)rg * 128;
#pragma unroll
      for (int f = 0; f < 8; ++f) {
        int col = f * 16 + l16;
        op[col] = (o[f] - mu) * rs * gv[f] + bev[f] + resid[col];
      }
    }
  }
}

extern "C" void kernel_launch(void* const* d_in, const int* in_sizes, int n_in,
                              void* d_out, int out_size, void* d_ws, size_t ws_size,
                              hipStream_t stream) {
  const float* node_emb = (const float*)d_in[0];
  const float* edge_emb = (const float*)d_in[1];
  const int*   src      = (const int*)d_in[2];
  const int*   dst      = (const int*)d_in[3];
  const float* eW1 = (const float*)d_in[5];
  const float* eb1 = (const float*)d_in[6];
  const float* eW2 = (const float*)d_in[7];
  const float* eb2 = (const float*)d_in[8];
  const float* eW3 = (const float*)d_in[9];
  const float* eb3 = (const float*)d_in[10];
  const float* eg  = (const float*)d_in[11];
  const float* ebt = (const float*)d_in[12];
  const float* nW1 = (const float*)d_in[13];
  const float* nb1 = (const float*)d_in[14];
  const float* nW2 = (const float*)d_in[15];
  const float* nb2 = (const float*)d_in[16];
  const float* nW3 = (const float*)d_in[17];
  const float* nb3 = (const float*)d_in[18];
  const float* ng  = (const float*)d_in[19];
  const float* nbt = (const float*)d_in[20];

  const int Nn = in_sizes[0] / 128;
  const int Ee = in_sizes[2];
  const int nb2048 = (Nn + 2047) / 2048;   // <= 64 required by bscan_kernel

  char* ws = (char*)d_ws;
  short* aggb   = (short*)ws;  ws += (size_t)Nn * 128 * 2;
  short* nodebf = (short*)ws;  ws += (size_t)Nn * 128 * 2;
  int* cnt_i  = (int*)ws;      ws += (size_t)Nn * 4;
  int* cursor = (int*)ws;      ws += (size_t)Nn * 4;
  int* offv   = (int*)ws;      ws += (size_t)(Nn + 1) * 4;
  int* eidx   = (int*)ws;      ws += (size_t)Ee * 4;
  int* bsum   = (int*)ws;      ws += 64 * 4;
  ws = (char*)(((uintptr_t)ws + 15) & ~(uintptr_t)15);
  short* eAll = (short*)ws;          // W1 12x8192 | W2 8x8192 | W3 8x4096 = 196608 shorts
  short* nAll = eAll + 196608;       // W1 8x8192 | W2 8x8192 | W3 8x4096 = 163840 shorts

  float* out_node = (float*)d_out;
  float* out_edge = out_node + (size_t)Nn * 128;

  hipMemsetAsync(cnt_i, 0, (size_t)Nn * 4, stream);

  cvt_count_kernel<<<2048, 256, 0, stream>>>(node_emb, nodebf, (long)Nn * 16, dst, cnt_i, Ee);
  prep_all_kernel<<<176, 256, 0, stream>>>(eW1, eW2, eW3, nW1, nW2, nW3, eAll, nAll);

  bsum_kernel<<<nb2048, 256, 0, stream>>>(cnt_i, bsum, Nn);
  bscan_kernel<<<1, 64, 0, stream>>>(bsum, nb2048);
  offs_kernel<<<nb2048, 256, 0, stream>>>(cnt_i, bsum, offv, cursor, Nn);
  scatter_kernel<<<(Ee + 255) / 256, 256, 0, stream>>>(dst, cursor, eidx, Ee);

  mlp_kernel<true><<<(Ee + 127) / 128, 512, 114688, stream>>>(
      node_emb, edge_emb, nodebf, aggb, src, dst, eAll,
      eb1, eb2, eb3, eg, ebt, out_edge, Ee);

  agg_kernel<<<(Nn + 3) / 4, 256, 0, stream>>>(out_edge, eidx, offv, aggb, Nn);

  mlp_kernel<false><<<(Nn + 127) / 128, 512, 114688, stream>>>(
      node_emb, edge_emb, nodebf, aggb, src, dst, nAll,
      nb1, nb2, nb3, ng, nbt, out_node, Nn);
}